// Round 5
// baseline (481.066 us; speedup 1.0000x reference)
//
#include <hip/hip_runtime.h>
#include <hip/hip_bf16.h>
#include <math.h>

// FEAf lowpass: b=4, t=2048, c=64, mw=64, modes=16, SCALE=1/4096.
// Stage A v4: BARRIER-FREE wave-private pipeline. Each wave owns a 64-float
//   dh slice; lane l stages t-step (l>>4), float4 col (l&15) into a
//   wave-private LDS tile (intra-wave transpose; DS pipe is in-order per
//   wave -> no __syncthreads anywhere). 2-deep software pipeline: loads for
//   phase ph+2 issue before phase ph's FMAs -> ~2 compute-phases (~900 cy)
//   of latency slack per wave, x20 waves/CU independent.
// reduceP: sum chunk partials (CH=8, 50 MB of P traffic).
// Stage B: per (b,h) complex 16x16 attention w/ complex tanh.
// Stage C: 16-mode inverse (radix-2 Hermitian over t), TT=16.

#define T_DIM 2048
#define DH 4096           // c*mw
#define DH2 2048          // float2 view
#define CH 8              // stageA chunks over t' in [0,512)
#define TPCH 64           // t' per chunk
#define NPH 16            // phases per chunk (4 t-steps each)
#define TT 16             // stageC t-tile

__device__ inline float4 f4add(float4 a, float4 b) {
    return make_float4(a.x + b.x, a.y + b.y, a.z + b.z, a.w + b.w);
}
__device__ inline float4 f4sub(float4 a, float4 b) {
    return make_float4(a.x - b.x, a.y - b.y, a.z - b.z, a.w - b.w);
}

// ---------------- twiddle tables ----------------
// WA[t'][2m]=cos(2pi m t'/2048), WA[t'][2m+1]=sin(...)           (t' in [0,512))
// Bt2[t][2m]=coef_m cos(2pi m t/2048), [2m+1]=-coef_m sin(...)   (t in [0,1024))
__global__ void init_tables(float* __restrict__ WA, float* __restrict__ Bt2) {
    int i = blockIdx.x * 256 + threadIdx.x;
    const float TWO_PI = 6.2831853071795864769f;
    if (i < 512 * 32) {
        int t = i >> 5, r = i & 31, m = r >> 1;
        int ph = (m * t) & 2047;
        float ang = TWO_PI * (float)ph * (1.0f / 2048.0f);
        WA[i] = (r & 1) ? sinf(ang) : cosf(ang);
    }
    int i2 = i - 512 * 32;
    if (i2 >= 0 && i2 < 1024 * 32) {
        int t = i2 >> 5, r = i2 & 31, m = r >> 1;
        int ph = (m * t) & 2047;
        float ang = TWO_PI * (float)ph * (1.0f / 2048.0f);
        const float S2 = 1.0f / (4096.0f * 2048.0f);
        float coef = (m == 0 ? 1.0f : 2.0f) * S2;
        float val;
        if (!(r & 1)) val = coef * cosf(ang);
        else          val = (m == 0) ? 0.0f : -coef * sinf(ang);
        Bt2[i2] = val;
    }
}

// ---------------- stage A ----------------
// P[tz][chunk][j][dh]; j: 0..15 Re, 16..31 Im. tz = tensor*4 + b.

// load the 4 radix-quarters of phase PH (lane l: t-step l>>4, f4-col l&15)
#define LOADP(PH, X0, X1, X2, X3) do {                                         \
    size_t t0 = (size_t)(tbase + (PH) * 4);                                    \
    X0 = src4[t0 * 1024 + f4];                                                 \
    X1 = src4[(t0 + 512) * 1024 + f4];                                         \
    X2 = src4[(t0 + 1024) * 1024 + f4];                                        \
    X3 = src4[(t0 + 1536) * 1024 + f4];                                        \
} while (0)

// radix-4 fold + write to wave-private LDS buffer BUF
#define FOLDW(BUF, X0, X1, X2, X3) do {                                        \
    float4 fu0 = f4add(X0, X2), fu1 = f4add(X1, X3);                           \
    float4 fd0 = f4sub(X0, X2), fd1 = f4sub(X1, X3);                           \
    wslab[(BUF) * 256 + 0 * 64 + widx] = f4add(fu0, fu1);                      \
    wslab[(BUF) * 256 + 1 * 64 + widx] = f4sub(fu0, fu1);                      \
    wslab[(BUF) * 256 + 2 * 64 + widx] = fd0;                                  \
    wslab[(BUF) * 256 + 3 * 64 + widx] = fd1;                                  \
} while (0)

// accumulate 16 modes for this thread's dh float, phase PH, from buffer BUF
#define COMP(BUF, PH) do {                                                     \
    _Pragma("unroll")                                                          \
    for (int i = 0; i < 4; i++) {                                              \
        float ee  = elds[iw][BUF][0][i][lane];                                 \
        float ff  = elds[iw][BUF][1][i][lane];                                 \
        float dd0 = elds[iw][BUF][2][i][lane];                                 \
        float dd1 = elds[iw][BUF][3][i][lane];                                 \
        const float* tw = WA + (size_t)(c * TPCH + (PH) * 4 + i) * 32;         \
        _Pragma("unroll")                                                      \
        for (int m = 0; m < 16; m++) {                                         \
            float cm = tw[2 * m], sm = tw[2 * m + 1];                          \
            if ((m & 3) == 0) {                                                \
                accR[m] = fmaf(cm, ee, accR[m]);                               \
                accI[m] = fmaf(-sm, ee, accI[m]);                              \
            } else if ((m & 3) == 2) {                                         \
                accR[m] = fmaf(cm, ff, accR[m]);                               \
                accI[m] = fmaf(-sm, ff, accI[m]);                              \
            } else if ((m & 3) == 1) {                                         \
                accR[m] = fmaf(cm, dd0, fmaf(-sm, dd1, accR[m]));              \
                accI[m] = fmaf(-sm, dd0, fmaf(-cm, dd1, accI[m]));             \
            } else {                                                           \
                accR[m] = fmaf(cm, dd0, fmaf(sm, dd1, accR[m]));               \
                accI[m] = fmaf(-sm, dd0, fmaf(cm, dd1, accI[m]));              \
            }                                                                  \
        }                                                                      \
    }                                                                          \
} while (0)

__global__ __launch_bounds__(256) void stageA(
        const float* __restrict__ q, const float* __restrict__ k,
        const float* __restrict__ v, const float* __restrict__ WA,
        float* __restrict__ P) {
    // wave-private double-buffered fold tiles:
    // elds[iw][buf][arr e/f/d0/d1][t-step i][64 dh floats]  = 32 KB total
    __shared__ float elds[4][2][4][4][64];

    int tid  = threadIdx.x;
    int iw   = tid >> 6;          // wave id
    int lane = tid & 63;
    int li   = lane >> 4;         // t-step within phase
    int lc   = lane & 15;         // float4 column within wave's dh slice
    int bx   = blockIdx.x;        // dh tile [0,16), 256 floats each
    int c    = blockIdx.y;        // chunk [0,CH)
    int tz   = blockIdx.z;
    int tensor = tz >> 2, b = tz & 3;

    const float* srcf = (tensor == 0 ? q : tensor == 1 ? k : v)
                        + (size_t)b * T_DIM * DH;
    const float4* src4 = (const float4*)srcf;     // 1024 float4 per t-row
    const int f4    = bx * 64 + iw * 16 + lc;     // float4 col within row
    const int tbase = c * TPCH + li;

    float4* wslab = (float4*)&elds[iw][0][0][0][0];  // this wave's 8 KB slab
    const int widx = li * 16 + lc;

    float accR[16], accI[16];
    #pragma unroll
    for (int m = 0; m < 16; m++) { accR[m] = 0.f; accI[m] = 0.f; }

    float4 a0, a1, a2, a3, b0, b1, b2, b3;

    // ---- prologue: fill buf0 with phase 0; phase 1 loads in flight ----
    LOADP(0, a0, a1, a2, a3);
    FOLDW(0, a0, a1, a2, a3);
    LOADP(1, b0, b1, b2, b3);

    // ---- main loop: no barriers; 2-deep load pipeline per wave ----
    for (int ph = 0; ph < NPH - 2; ph += 2) {
        LOADP(ph + 2, a0, a1, a2, a3);   // issue 2 phases ahead
        COMP(0, ph);
        FOLDW(1, b0, b1, b2, b3);        // consume phase ph+1 loads
        LOADP(ph + 3, b0, b1, b2, b3);
        COMP(1, ph + 1);
        FOLDW(0, a0, a1, a2, a3);        // consume phase ph+2 loads
    }
    COMP(0, NPH - 2);
    FOLDW(1, b0, b1, b2, b3);
    COMP(1, NPH - 1);

    // ---- store partials: this thread's dh float for all 32 j ----
    float* pp = P + ((size_t)(tz * CH + c) * 32) * DH + bx * 256 + tid;
    #pragma unroll
    for (int m = 0; m < 16; m++) {
        pp[(size_t)m * DH]        = accR[m];
        pp[(size_t)(16 + m) * DH] = accI[m];
    }
}

// ---------------- reduce chunk partials: Y[tz][j][dh] ----------------
__global__ __launch_bounds__(256) void reduceP(const float4* __restrict__ P,
                                               float4* __restrict__ Y) {
    size_t i   = (size_t)blockIdx.x * 256 + threadIdx.x;  // 12*32*1024
    size_t tzj = i >> 10;
    size_t dh4 = i & 1023;
    size_t tz  = tzj >> 5;
    size_t j   = tzj & 31;
    const float4* p = P + ((tz * CH) * 32 + j) * 1024 + dh4;
    float4 s = make_float4(0.f, 0.f, 0.f, 0.f);
    #pragma unroll
    for (int cc = 0; cc < CH; cc++) {
        float4 t = p[(size_t)cc * 32 * 1024];
        s.x += t.x; s.y += t.y; s.z += t.z; s.w += t.w;
    }
    Y[i] = s;
}

// ---------------- stage B: complex mode-space attention ----------------
// G[b][j][dh], j: 0..15 Re(qkv), 16..31 Im(qkv)
__global__ __launch_bounds__(256) void stageB(const float* __restrict__ Y,
                                              float* __restrict__ G) {
    __shared__ float qf[64 * 33];
    __shared__ float kf[64 * 33];
    __shared__ float vf[64 * 33];
    __shared__ float qkr[16 * 17];
    __shared__ float qki[16 * 17];

    int tid = threadIdx.x;
    int bh  = blockIdx.x;
    int b   = bh >> 6;
    int h   = bh & 63;

    #pragma unroll
    for (int tensor = 0; tensor < 3; tensor++) {
        float* dst = (tensor == 0 ? qf : tensor == 1 ? kf : vf);
        const float* yp = Y + ((size_t)(tensor * 4 + b) * 32) * DH + h;
        #pragma unroll
        for (int it = 0; it < 8; it++) {
            int p = it * 256 + tid;
            int d = p & 63, j = p >> 6;
            dst[d * 33 + j] = yp[(size_t)j * DH + d * 64];
        }
    }
    __syncthreads();

    int x = tid >> 4, y = tid & 15;
    float ar = 0.f, ai = 0.f;
    #pragma unroll 4
    for (int d = 0; d < 64; d++) {
        float qr = qf[d * 33 + x],      qi = qf[d * 33 + 16 + x];
        float kr = kf[d * 33 + y],      ki = kf[d * 33 + 16 + y];
        ar += qr * kr - qi * ki;
        ai += qr * ki + qi * kr;
    }
    float re, im;
    float a2 = 2.f * ar, b2 = 2.f * ai;
    if (fabsf(a2) < 80.f) {
        float den = coshf(a2) + cosf(b2);
        re = sinhf(a2) / den;
        im = sinf(b2) / den;
    } else {
        re = copysignf(1.f, ar);
        im = 0.f;
    }
    qkr[x * 17 + y] = re;
    qki[x * 17 + y] = im;
    __syncthreads();

    int xx = tid & 15, db = tid >> 4;
    #pragma unroll
    for (int i = 0; i < 4; i++) {
        int d = db + i * 16;
        float cr = 0.f, ci = 0.f;
        #pragma unroll
        for (int yy = 0; yy < 16; yy++) {
            float tr = qkr[xx * 17 + yy], ti = qki[xx * 17 + yy];
            float vr = vf[d * 33 + yy],   vi = vf[d * 33 + 16 + yy];
            cr += tr * vr - ti * vi;
            ci += tr * vi + ti * vr;
        }
        G[((size_t)b * 32 + xx) * DH + d * 64 + h]      = cr;
        G[((size_t)b * 32 + 16 + xx) * DH + d * 64 + h] = ci;
    }
}

// ---------------- stage C: inverse, radix-2 Hermitian over t ----------------
// NOTE: no min-waves launch_bounds — gr/gi is 64 floats/thread (round-1 spill).
__global__ __launch_bounds__(256) void stageC(const float* __restrict__ G,
                                              const float* __restrict__ Bt2,
                                              float* __restrict__ out) {
    __shared__ float w[TT * 32];   // 2 KB basis tile
    int tid = threadIdx.x;
    int c   = blockIdx.y;          // t-tile over [0,1024), 64 tiles
    int b   = blockIdx.z;

    #pragma unroll
    for (int it = 0; it < TT * 32 / 256; it++)
        w[it * 256 + tid] = Bt2[c * (TT * 32) + it * 256 + tid];
    __syncthreads();

    int dh2 = blockIdx.x * 256 + tid;
    float2 gr[16], gi[16];
    const float2* gp = (const float2*)G + (size_t)b * 32 * DH2 + dh2;
    #pragma unroll
    for (int m = 0; m < 16; m++) {
        gr[m] = gp[(size_t)m * DH2];
        gi[m] = gp[(size_t)(16 + m) * DH2];
    }

    float2* o0 = (float2*)out + ((size_t)b * T_DIM + (size_t)c * TT) * DH2 + dh2;
    #pragma unroll 2
    for (int tl = 0; tl < TT; tl++) {
        const float* ww = &w[tl * 32];
        float2 E = make_float2(0.f, 0.f), O = make_float2(0.f, 0.f);
        #pragma unroll
        for (int m = 0; m < 16; m += 2) {
            E.x = fmaf(ww[2 * m],     gr[m].x, E.x);
            E.x = fmaf(ww[2 * m + 1], gi[m].x, E.x);
            E.y = fmaf(ww[2 * m],     gr[m].y, E.y);
            E.y = fmaf(ww[2 * m + 1], gi[m].y, E.y);
        }
        #pragma unroll
        for (int m = 1; m < 16; m += 2) {
            O.x = fmaf(ww[2 * m],     gr[m].x, O.x);
            O.x = fmaf(ww[2 * m + 1], gi[m].x, O.x);
            O.y = fmaf(ww[2 * m],     gr[m].y, O.y);
            O.y = fmaf(ww[2 * m + 1], gi[m].y, O.y);
        }
        o0[(size_t)tl * DH2] = make_float2(E.x + O.x, E.y + O.y);
        o0[(size_t)(tl + 1024) * DH2] = make_float2(E.x - O.x, E.y - O.y);
    }
}

extern "C" void kernel_launch(void* const* d_in, const int* in_sizes, int n_in,
                              void* d_out, int out_size, void* d_ws, size_t ws_size,
                              hipStream_t stream) {
    const float* q = (const float*)d_in[0];
    const float* k = (const float*)d_in[1];
    const float* v = (const float*)d_in[2];
    float* out = (float*)d_out;

    char* ws = (char*)d_ws;
    float* WA  = (float*)ws;                         //    65536 B
    float* Bt2 = (float*)(ws + 65536);               //   131072 B
    const size_t base = 65536 + 131072;

    const size_t psz = (size_t)12 * CH * 32 * DH * 4;   // 50331648 B
    const size_t ysz = 6291456;
    float* P = (float*)(ws + base);
    float* Y = (float*)(ws + base + psz);
    float* G = (float*)(ws + base + psz + ysz);

    init_tables<<<192, 256, 0, stream>>>(WA, Bt2);
    stageA<<<dim3(16, CH, 12), 256, 0, stream>>>(q, k, v, WA, P);
    reduceP<<<1536, 256, 0, stream>>>((const float4*)P, (float4*)Y);
    stageB<<<256, 256, 0, stream>>>(Y, G);
    stageC<<<dim3(8, 64, 4), 256, 0, stream>>>(G, Bt2, out);
}

// Round 6
// 469.096 us; speedup vs baseline: 1.0255x; 1.0255x over previous
//
#include <hip/hip_runtime.h>
#include <hip/hip_bf16.h>
#include <math.h>

// FEAf lowpass: b=4, t=2048, c=64, mw=64, modes=16, SCALE=1/4096.
// Stage A v5: async global_load_lds staging (T3/T4 pattern).
//   Raw quarter-rows DMA'd to LDS (zero VGPRs held by in-flight data ->
//   compiler cannot un-pipeline, unlike v4's register prefetch which it
//   sank: VGPR=52 proved the pipeline regs were never held).
//   Double-buffered 2x16KB, counted s_waitcnt vmcnt(4) + raw s_barrier
//   (never vmcnt(0) mid-loop; 8 loads/wave in flight across barriers).
//   Fold (radix-4) done per-thread at read time (+6 VALU per 4-row step).
// reduceP / stageB / stageC: identical to round-4 passing build.

#define T_DIM 2048
#define DH 4096           // c*mw
#define DH2 2048          // float2 view
#define CH 8              // stageA chunks over t' in [0,512)
#define TPCH 64           // t' per chunk
#define NPH 16            // phases per chunk (4 t-steps each)
#define TT 16             // stageC t-tile

// ---------------- twiddle tables ----------------
// WA[t'][2m]=cos(2pi m t'/2048), WA[t'][2m+1]=sin(...)           (t' in [0,512))
// Bt2[t][2m]=coef_m cos(2pi m t/2048), [2m+1]=-coef_m sin(...)   (t in [0,1024))
__global__ void init_tables(float* __restrict__ WA, float* __restrict__ Bt2) {
    int i = blockIdx.x * 256 + threadIdx.x;
    const float TWO_PI = 6.2831853071795864769f;
    if (i < 512 * 32) {
        int t = i >> 5, r = i & 31, m = r >> 1;
        int ph = (m * t) & 2047;
        float ang = TWO_PI * (float)ph * (1.0f / 2048.0f);
        WA[i] = (r & 1) ? sinf(ang) : cosf(ang);
    }
    int i2 = i - 512 * 32;
    if (i2 >= 0 && i2 < 1024 * 32) {
        int t = i2 >> 5, r = i2 & 31, m = r >> 1;
        int ph = (m * t) & 2047;
        float ang = TWO_PI * (float)ph * (1.0f / 2048.0f);
        const float S2 = 1.0f / (4096.0f * 2048.0f);
        float coef = (m == 0 ? 1.0f : 2.0f) * S2;
        float val;
        if (!(r & 1)) val = coef * cosf(ang);
        else          val = (m == 0) ? 0.0f : -coef * sinf(ang);
        Bt2[i2] = val;
    }
}

// async 16B-per-lane global -> LDS (wave-uniform LDS base; lane l lands at
// base + l*16). Size must be a literal (not template-dependent).
__device__ __forceinline__ void async16(const void* gptr, void* lptr) {
    __builtin_amdgcn_global_load_lds(
        (const __attribute__((address_space(1))) unsigned int*)gptr,
        (__attribute__((address_space(3))) unsigned int*)lptr,
        16, 0, 0);
}

// ---------------- stage A ----------------
// P[tz][chunk][j][dh]; j: 0..15 Re, 16..31 Im. tz = tensor*4 + b.

// wave iw stages t-step iw of phase PH: 4 quarter-rows, 1 KB linear each
#define STAGE(PH, BUF) do {                                                    \
    size_t t0 = (size_t)(c * TPCH + (PH) * 4 + iw);                            \
    async16(&src4[t0 * 1024 + gcol],          &tile[BUF][iw][0][0]);           \
    async16(&src4[(t0 + 512) * 1024 + gcol],  &tile[BUF][iw][1][0]);           \
    async16(&src4[(t0 + 1024) * 1024 + gcol], &tile[BUF][iw][2][0]);           \
    async16(&src4[(t0 + 1536) * 1024 + gcol], &tile[BUF][iw][3][0]);           \
} while (0)

// accumulate 16 modes for this thread's dh float from buffer BUF, phase PH
#define COMP(BUF, PH) do {                                                     \
    _Pragma("unroll")                                                          \
    for (int i = 0; i < 4; i++) {                                              \
        const float* tp = (const float*)&tile[BUF][i][0][0];                   \
        float x0 = tp[tid], x1 = tp[256 + tid];                                \
        float x2 = tp[512 + tid], x3 = tp[768 + tid];                          \
        float fu0 = x0 + x2, fu1 = x1 + x3;                                    \
        float ee  = fu0 + fu1, ff = fu0 - fu1;                                 \
        float dd0 = x0 - x2, dd1 = x1 - x3;                                    \
        const float* tw = WA + (size_t)(c * TPCH + (PH) * 4 + i) * 32;         \
        _Pragma("unroll")                                                      \
        for (int m = 0; m < 16; m++) {                                         \
            float cm = tw[2 * m], sm = tw[2 * m + 1];                          \
            if ((m & 3) == 0) {                                                \
                accR[m] = fmaf(cm, ee, accR[m]);                               \
                accI[m] = fmaf(-sm, ee, accI[m]);                              \
            } else if ((m & 3) == 2) {                                         \
                accR[m] = fmaf(cm, ff, accR[m]);                               \
                accI[m] = fmaf(-sm, ff, accI[m]);                              \
            } else if ((m & 3) == 1) {                                         \
                accR[m] = fmaf(cm, dd0, fmaf(-sm, dd1, accR[m]));              \
                accI[m] = fmaf(-sm, dd0, fmaf(-cm, dd1, accI[m]));             \
            } else {                                                           \
                accR[m] = fmaf(cm, dd0, fmaf(sm, dd1, accR[m]));               \
                accI[m] = fmaf(-sm, dd0, fmaf(cm, dd1, accI[m]));              \
            }                                                                  \
        }                                                                      \
    }                                                                          \
} while (0)

__global__ __launch_bounds__(256) void stageA(
        const float* __restrict__ q, const float* __restrict__ k,
        const float* __restrict__ v, const float* __restrict__ WA,
        float* __restrict__ P) {
    // tile[buf][t-step i][quarter r][64 float4] = 2 x 16 KB
    __shared__ float4 tile[2][4][4][64];

    int tid  = threadIdx.x;
    int iw   = tid >> 6;          // wave id = staged t-step
    int lane = tid & 63;
    int bx   = blockIdx.x;        // dh tile [0,16), 256 floats each
    int c    = blockIdx.y;        // chunk [0,CH)
    int tz   = blockIdx.z;
    int tensor = tz >> 2, b = tz & 3;

    const float* srcf = (tensor == 0 ? q : tensor == 1 ? k : v)
                        + (size_t)b * T_DIM * DH;
    const float4* src4 = (const float4*)srcf;   // 1024 float4 per t-row
    const int gcol = bx * 64 + lane;            // float4 col within row

    float accR[16], accI[16];
    #pragma unroll
    for (int m = 0; m < 16; m++) { accR[m] = 0.f; accI[m] = 0.f; }

    // ---- prologue: phases 0,1 in flight (8 loads/wave) ----
    STAGE(0, 0);
    STAGE(1, 1);

    // ---- main loop: counted vmcnt, raw barriers, 2-deep async pipeline ----
    for (int ph = 0; ph < NPH; ph += 2) {
        asm volatile("s_waitcnt vmcnt(4)" ::: "memory");  // phase ph landed
        __builtin_amdgcn_s_barrier();
        COMP(0, ph);
        __builtin_amdgcn_s_barrier();                     // buf0 fully read
        if (ph + 2 < NPH) STAGE(ph + 2, 0);

        if (ph + 3 < NPH) { asm volatile("s_waitcnt vmcnt(4)" ::: "memory"); }
        else              { asm volatile("s_waitcnt vmcnt(0)" ::: "memory"); }
        __builtin_amdgcn_s_barrier();
        COMP(1, ph + 1);
        __builtin_amdgcn_s_barrier();                     // buf1 fully read
        if (ph + 3 < NPH) STAGE(ph + 3, 1);
    }

    // ---- store partials: this thread's dh float for all 32 j ----
    float* pp = P + ((size_t)(tz * CH + c) * 32) * DH + bx * 256 + tid;
    #pragma unroll
    for (int m = 0; m < 16; m++) {
        pp[(size_t)m * DH]        = accR[m];
        pp[(size_t)(16 + m) * DH] = accI[m];
    }
}

// ---------------- reduce chunk partials: Y[tz][j][dh] ----------------
__global__ __launch_bounds__(256) void reduceP(const float4* __restrict__ P,
                                               float4* __restrict__ Y) {
    size_t i   = (size_t)blockIdx.x * 256 + threadIdx.x;  // 12*32*1024
    size_t tzj = i >> 10;
    size_t dh4 = i & 1023;
    size_t tz  = tzj >> 5;
    size_t j   = tzj & 31;
    const float4* p = P + ((tz * CH) * 32 + j) * 1024 + dh4;
    float4 s = make_float4(0.f, 0.f, 0.f, 0.f);
    #pragma unroll
    for (int cc = 0; cc < CH; cc++) {
        float4 t = p[(size_t)cc * 32 * 1024];
        s.x += t.x; s.y += t.y; s.z += t.z; s.w += t.w;
    }
    Y[i] = s;
}

// ---------------- stage B: complex mode-space attention ----------------
// G[b][j][dh], j: 0..15 Re(qkv), 16..31 Im(qkv)
__global__ __launch_bounds__(256) void stageB(const float* __restrict__ Y,
                                              float* __restrict__ G) {
    __shared__ float qf[64 * 33];
    __shared__ float kf[64 * 33];
    __shared__ float vf[64 * 33];
    __shared__ float qkr[16 * 17];
    __shared__ float qki[16 * 17];

    int tid = threadIdx.x;
    int bh  = blockIdx.x;
    int b   = bh >> 6;
    int h   = bh & 63;

    #pragma unroll
    for (int tensor = 0; tensor < 3; tensor++) {
        float* dst = (tensor == 0 ? qf : tensor == 1 ? kf : vf);
        const float* yp = Y + ((size_t)(tensor * 4 + b) * 32) * DH + h;
        #pragma unroll
        for (int it = 0; it < 8; it++) {
            int p = it * 256 + tid;
            int d = p & 63, j = p >> 6;
            dst[d * 33 + j] = yp[(size_t)j * DH + d * 64];
        }
    }
    __syncthreads();

    int x = tid >> 4, y = tid & 15;
    float ar = 0.f, ai = 0.f;
    #pragma unroll 4
    for (int d = 0; d < 64; d++) {
        float qr = qf[d * 33 + x],      qi = qf[d * 33 + 16 + x];
        float kr = kf[d * 33 + y],      ki = kf[d * 33 + 16 + y];
        ar += qr * kr - qi * ki;
        ai += qr * ki + qi * kr;
    }
    float re, im;
    float a2 = 2.f * ar, b2 = 2.f * ai;
    if (fabsf(a2) < 80.f) {
        float den = coshf(a2) + cosf(b2);
        re = sinhf(a2) / den;
        im = sinf(b2) / den;
    } else {
        re = copysignf(1.f, ar);
        im = 0.f;
    }
    qkr[x * 17 + y] = re;
    qki[x * 17 + y] = im;
    __syncthreads();

    int xx = tid & 15, db = tid >> 4;
    #pragma unroll
    for (int i = 0; i < 4; i++) {
        int d = db + i * 16;
        float cr = 0.f, ci = 0.f;
        #pragma unroll
        for (int yy = 0; yy < 16; yy++) {
            float tr = qkr[xx * 17 + yy], ti = qki[xx * 17 + yy];
            float vr = vf[d * 33 + yy],   vi = vf[d * 33 + 16 + yy];
            cr += tr * vr - ti * vi;
            ci += tr * vi + ti * vr;
        }
        G[((size_t)b * 32 + xx) * DH + d * 64 + h]      = cr;
        G[((size_t)b * 32 + 16 + xx) * DH + d * 64 + h] = ci;
    }
}

// ---------------- stage C: inverse, radix-2 Hermitian over t ----------------
// NOTE: no min-waves launch_bounds — gr/gi is 64 floats/thread (round-1 spill).
__global__ __launch_bounds__(256) void stageC(const float* __restrict__ G,
                                              const float* __restrict__ Bt2,
                                              float* __restrict__ out) {
    __shared__ float w[TT * 32];   // 2 KB basis tile
    int tid = threadIdx.x;
    int c   = blockIdx.y;          // t-tile over [0,1024), 64 tiles
    int b   = blockIdx.z;

    #pragma unroll
    for (int it = 0; it < TT * 32 / 256; it++)
        w[it * 256 + tid] = Bt2[c * (TT * 32) + it * 256 + tid];
    __syncthreads();

    int dh2 = blockIdx.x * 256 + tid;
    float2 gr[16], gi[16];
    const float2* gp = (const float2*)G + (size_t)b * 32 * DH2 + dh2;
    #pragma unroll
    for (int m = 0; m < 16; m++) {
        gr[m] = gp[(size_t)m * DH2];
        gi[m] = gp[(size_t)(16 + m) * DH2];
    }

    float2* o0 = (float2*)out + ((size_t)b * T_DIM + (size_t)c * TT) * DH2 + dh2;
    #pragma unroll 2
    for (int tl = 0; tl < TT; tl++) {
        const float* ww = &w[tl * 32];
        float2 E = make_float2(0.f, 0.f), O = make_float2(0.f, 0.f);
        #pragma unroll
        for (int m = 0; m < 16; m += 2) {
            E.x = fmaf(ww[2 * m],     gr[m].x, E.x);
            E.x = fmaf(ww[2 * m + 1], gi[m].x, E.x);
            E.y = fmaf(ww[2 * m],     gr[m].y, E.y);
            E.y = fmaf(ww[2 * m + 1], gi[m].y, E.y);
        }
        #pragma unroll
        for (int m = 1; m < 16; m += 2) {
            O.x = fmaf(ww[2 * m],     gr[m].x, O.x);
            O.x = fmaf(ww[2 * m + 1], gi[m].x, O.x);
            O.y = fmaf(ww[2 * m],     gr[m].y, O.y);
            O.y = fmaf(ww[2 * m + 1], gi[m].y, O.y);
        }
        o0[(size_t)tl * DH2] = make_float2(E.x + O.x, E.y + O.y);
        o0[(size_t)(tl + 1024) * DH2] = make_float2(E.x - O.x, E.y - O.y);
    }
}

extern "C" void kernel_launch(void* const* d_in, const int* in_sizes, int n_in,
                              void* d_out, int out_size, void* d_ws, size_t ws_size,
                              hipStream_t stream) {
    const float* q = (const float*)d_in[0];
    const float* k = (const float*)d_in[1];
    const float* v = (const float*)d_in[2];
    float* out = (float*)d_out;

    char* ws = (char*)d_ws;
    float* WA  = (float*)ws;                         //    65536 B
    float* Bt2 = (float*)(ws + 65536);               //   131072 B
    const size_t base = 65536 + 131072;

    const size_t psz = (size_t)12 * CH * 32 * DH * 4;   // 50331648 B
    const size_t ysz = 6291456;
    float* P = (float*)(ws + base);
    float* Y = (float*)(ws + base + psz);
    float* G = (float*)(ws + base + psz + ysz);

    init_tables<<<192, 256, 0, stream>>>(WA, Bt2);
    stageA<<<dim3(16, CH, 12), 256, 0, stream>>>(q, k, v, WA, P);
    reduceP<<<1536, 256, 0, stream>>>((const float4*)P, (float4*)Y);
    stageB<<<256, 256, 0, stream>>>(Y, G);
    stageC<<<dim3(8, 64, 4), 256, 0, stream>>>(G, Bt2, out);
}